// Round 1
// baseline (335.865 us; speedup 1.0000x reference)
//
#include <hip/hip_runtime.h>

// Problem constants (match reference)
#define B_    128
#define G_    12000
#define K_    512
#define H_    64
#define NCH   96        // histogram chunks
#define CHUNK 125       // 96*125 = 12000 rows
#define CSC_CAP (1 << 18)  // 262144 slots; expected nnz ~122880

// ---------------- k_hist: per-(chunk, column) nonzero counts of M ----------
__global__ void k_hist(const float* __restrict__ M, int* __restrict__ hist) {
    int c = blockIdx.x, k = threadIdx.x;
    const float* Mp = M + (size_t)c * CHUNK * K_ + k;
    int cnt = 0;
    for (int r = 0; r < CHUNK; ++r) cnt += (Mp[(size_t)r * K_] != 0.0f);
    hist[c * K_ + k] = cnt;
}

// ---------------- k_scan: column totals -> inv_deg, CSC bases; cvec --------
__global__ void k_scan(int* __restrict__ hist, int* __restrict__ colstart,
                       int* __restrict__ colcnt, float* __restrict__ invdeg,
                       float* __restrict__ cvec,
                       const int* __restrict__ cell_idx,
                       const float* __restrict__ cell_emb,
                       const float* __restrict__ W_out,
                       const float* __restrict__ b_out) {
    __shared__ int sd[K_];
    int k = threadIdx.x;
    int tot = 0;
    for (int c = 0; c < NCH; ++c) tot += hist[c * K_ + k];
    sd[k] = tot;
    __syncthreads();
    // inclusive Hillis-Steele scan over 512
    for (int off = 1; off < K_; off <<= 1) {
        int v = (k >= off) ? sd[k - off] : 0;
        __syncthreads();
        sd[k] += v;
        __syncthreads();
    }
    int start = sd[k] - tot;            // exclusive prefix
    colstart[k] = start;
    colcnt[k]   = tot;
    float deg = (float)tot;
    if (deg < 1.0f) deg = 1.0f;
    invdeg[k] = 1.0f / deg;
    // rewrite hist to absolute fill bases (per chunk)
    int run = start;
    for (int c = 0; c < NCH; ++c) {
        int t = hist[c * K_ + k];
        hist[c * K_ + k] = run;
        run += t;
    }
    // cvec[b] = cell_emb[cidx[b],:] . W_out + b_out
    if (k < B_) {
        int ci = cell_idx[k];
        float acc = b_out[0];
        for (int h = 0; h < H_; ++h) acc = fmaf(cell_emb[ci * H_ + h], W_out[h], acc);
        cvec[k] = acc;
    }
}

// ---------------- k_fill: deterministic CSC fill (g ascending per column) --
__global__ void k_fill(const float* __restrict__ M, const int* __restrict__ hist,
                       int* __restrict__ csc) {
    int c = blockIdx.x, k = threadIdx.x;
    int off = hist[c * K_ + k];
    const float* Mp = M + (size_t)c * CHUNK * K_ + k;
    for (int r = 0; r < CHUNK; ++r) {
        if (Mp[(size_t)r * K_] != 0.0f) {
            if (off < CSC_CAP) csc[off] = c * CHUNK + r;
            ++off;
        }
    }
}

// ---------------- k_trans: [B,G] -> [G,B] for ctl and drug_targets ---------
__global__ void k_trans(const float* __restrict__ ctl, const float* __restrict__ dt,
                        float* __restrict__ ctlT, float* __restrict__ dtT) {
    __shared__ float t[32][33];
    const float* src = blockIdx.z ? dt : ctl;
    float* dst = blockIdx.z ? dtT : ctlT;
    int g0 = blockIdx.x * 32, b0 = blockIdx.y * 32;
    int tx = threadIdx.x, ty = threadIdx.y;
#pragma unroll
    for (int j = 0; j < 4; ++j)
        t[ty + 8 * j][tx] = src[(size_t)(b0 + ty + 8 * j) * G_ + g0 + tx];
    __syncthreads();
#pragma unroll
    for (int j = 0; j < 4; ++j)
        dst[(size_t)(g0 + ty + 8 * j) * B_ + b0 + tx] = t[tx][ty + 8 * j];
}

// ---------------- k_gather: sparse x_mod + fused MLP -> s[k][b] ------------
// s[b,k] = sum_h relu(x0*Win[0,h] + x1*Win[1,h] + b_in[h]) * Wout[h]
__global__ void k_gather(const int* __restrict__ csc, const int* __restrict__ colstart,
                         const int* __restrict__ colcnt, const float* __restrict__ invdeg,
                         const float* __restrict__ ctlT, const float* __restrict__ dtT,
                         const float* __restrict__ W_in, const float* __restrict__ b_in,
                         const float* __restrict__ W_out, float* __restrict__ sout) {
    int k = blockIdx.x, b = threadIdx.x;
    int s0 = colstart[k], n = colcnt[k];
    float a0 = 0.f, a1 = 0.f;
    int j = 0;
    for (; j + 4 <= n; j += 4) {
        int g0 = csc[s0 + j + 0], g1 = csc[s0 + j + 1];
        int g2 = csc[s0 + j + 2], g3 = csc[s0 + j + 3];
        a0 += ctlT[g0 * B_ + b]; a1 += dtT[g0 * B_ + b];
        a0 += ctlT[g1 * B_ + b]; a1 += dtT[g1 * B_ + b];
        a0 += ctlT[g2 * B_ + b]; a1 += dtT[g2 * B_ + b];
        a0 += ctlT[g3 * B_ + b]; a1 += dtT[g3 * B_ + b];
    }
    for (; j < n; ++j) {
        int g = csc[s0 + j];
        a0 += ctlT[g * B_ + b]; a1 += dtT[g * B_ + b];
    }
    float inv = invdeg[k];
    float x0 = a0 * inv, x1 = a1 * inv;
    float s = 0.f;
#pragma unroll 8
    for (int h = 0; h < H_; ++h) {
        float v = fmaf(x0, W_in[h], fmaf(x1, W_in[H_ + h], b_in[h]));
        v = fmaxf(v, 0.f);
        s = fmaf(v, W_out[h], s);
    }
    sout[k * B_ + b] = s;   // [K][B] layout, coalesced
}

// ---------------- k_diff: one PPR step on z (layout [K][B]) ----------------
// zout_part[kc][l][b] = 0.9 * sum_{k in kc} z[k][b]*A[k][l]  (+0.1*s[l][b] if kc==0)
// zin is either the full [K][B] array (in_is_part=0) or 8 partials to sum.
__global__ void k_diff(const float* __restrict__ zin, int in_is_part,
                       const float* __restrict__ A, const float* __restrict__ sout,
                       float* __restrict__ zout) {
    __shared__ __align__(16) float zsT[64][36];   // [k-local][b-local(32)]
    __shared__ __align__(16) float As[64][68];    // [k-local][l-local(64)]
    int lt = blockIdx.x, bt = blockIdx.y, kc = blockIdx.z;
    int tid = threadIdx.x;                         // 128 threads
    int k0 = kc * 64, l0 = lt * 64, b0 = bt * 32;
    // load z tile: rows are k (coalesced along b)
#pragma unroll
    for (int i = 0; i < 16; ++i) {
        int lin = tid + i * 128;
        int r = lin & 31, c = lin >> 5;            // r: b-local, c: k-local
        int gi = (k0 + c) * B_ + b0 + r;
        float v;
        if (in_is_part) {
            v = 0.f;
#pragma unroll
            for (int p = 0; p < 8; ++p) v += zin[p * (K_ * B_) + gi];
        } else {
            v = zin[gi];
        }
        zsT[c][r] = v;
    }
    // load A tile [64 k][64 l]
#pragma unroll
    for (int i = 0; i < 32; ++i) {
        int lin = tid + i * 128;
        int cc = lin & 63, rr = lin >> 6;
        As[rr][cc] = A[(size_t)(k0 + rr) * K_ + l0 + cc];
    }
    __syncthreads();
    int lg = tid & 15, bg = tid >> 4;              // 16 l-groups x 8 b-groups
    float acc[4][4] = {};                          // [i: b][j: l]
#pragma unroll 8
    for (int kk = 0; kk < 64; ++kk) {
        const float4 av = *(const float4*)&As[kk][lg * 4];
        const float4 zv = *(const float4*)&zsT[kk][bg * 4];
        const float a0 = av.x, a1 = av.y, a2 = av.z, a3 = av.w;
        const float z0 = zv.x, z1 = zv.y, z2 = zv.z, z3 = zv.w;
        acc[0][0] = fmaf(z0, a0, acc[0][0]); acc[0][1] = fmaf(z0, a1, acc[0][1]);
        acc[0][2] = fmaf(z0, a2, acc[0][2]); acc[0][3] = fmaf(z0, a3, acc[0][3]);
        acc[1][0] = fmaf(z1, a0, acc[1][0]); acc[1][1] = fmaf(z1, a1, acc[1][1]);
        acc[1][2] = fmaf(z1, a2, acc[1][2]); acc[1][3] = fmaf(z1, a3, acc[1][3]);
        acc[2][0] = fmaf(z2, a0, acc[2][0]); acc[2][1] = fmaf(z2, a1, acc[2][1]);
        acc[2][2] = fmaf(z2, a2, acc[2][2]); acc[2][3] = fmaf(z2, a3, acc[2][3]);
        acc[3][0] = fmaf(z3, a0, acc[3][0]); acc[3][1] = fmaf(z3, a1, acc[3][1]);
        acc[3][2] = fmaf(z3, a2, acc[3][2]); acc[3][3] = fmaf(z3, a3, acc[3][3]);
    }
#pragma unroll
    for (int j = 0; j < 4; ++j) {
        int l = l0 + lg * 4 + j;
        float4 o;
        o.x = 0.9f * acc[0][j]; o.y = 0.9f * acc[1][j];
        o.z = 0.9f * acc[2][j]; o.w = 0.9f * acc[3][j];
        if (kc == 0) {
            const float4 sv = *(const float4*)&sout[l * B_ + b0 + bg * 4];
            o.x += 0.1f * sv.x; o.y += 0.1f * sv.y;
            o.z += 0.1f * sv.z; o.w += 0.1f * sv.w;
        }
        *(float4*)&zout[(size_t)kc * (K_ * B_) + l * B_ + b0 + bg * 4] = o;
    }
}

// ---------------- k_zred: sum 8 partials -> zfinal [K][B] ------------------
__global__ void k_zred(const float* __restrict__ zp, float* __restrict__ zf) {
    int idx = (blockIdx.x * 256 + threadIdx.x) * 4;
    float4 a = *(const float4*)&zp[idx];
#pragma unroll
    for (int p = 1; p < 8; ++p) {
        const float4 b = *(const float4*)&zp[p * (K_ * B_) + idx];
        a.x += b.x; a.y += b.y; a.z += b.z; a.w += b.w;
    }
    *(float4*)&zf[idx] = a;
}

// ---------------- k_out: y[b,g] = cvec[b] + sum_k zf[k][b]*M[g,k] ----------
__global__ void k_out(const float* __restrict__ zf, const float* __restrict__ M,
                      const float* __restrict__ cvec, float* __restrict__ y) {
    __shared__ __align__(16) float zsT[32][132];  // [k-local][b(128)]
    __shared__ __align__(16) float Ms[32][36];    // [k-local][g-local(32)]
    int g0 = blockIdx.x * 32;
    int tid = threadIdx.x;                         // 256 threads
    int gg = tid & 7, bg = tid >> 3;               // 8 g-groups x 32 b-groups
    float acc[4][4] = {};                          // [i: b][j: g]
    for (int kc = 0; kc < 16; ++kc) {
        int k0 = kc * 32;
#pragma unroll
        for (int i = 0; i < 16; ++i) {
            int lin = tid + i * 256;
            int r = lin & 127, c = lin >> 7;       // r: b, c: k-local
            zsT[c][r] = zf[(k0 + c) * B_ + r];
        }
#pragma unroll
        for (int i = 0; i < 4; ++i) {
            int l2 = tid + i * 256;
            int cc = l2 & 31, rr = l2 >> 5;
            Ms[cc][rr] = M[(size_t)(g0 + rr) * K_ + k0 + cc];
        }
        __syncthreads();
#pragma unroll 8
        for (int kk = 0; kk < 32; ++kk) {
            const float4 zv = *(const float4*)&zsT[kk][bg * 4];
            const float4 mv = *(const float4*)&Ms[kk][gg * 4];
            const float m0 = mv.x, m1 = mv.y, m2 = mv.z, m3 = mv.w;
            const float z0 = zv.x, z1 = zv.y, z2 = zv.z, z3 = zv.w;
            acc[0][0] = fmaf(z0, m0, acc[0][0]); acc[0][1] = fmaf(z0, m1, acc[0][1]);
            acc[0][2] = fmaf(z0, m2, acc[0][2]); acc[0][3] = fmaf(z0, m3, acc[0][3]);
            acc[1][0] = fmaf(z1, m0, acc[1][0]); acc[1][1] = fmaf(z1, m1, acc[1][1]);
            acc[1][2] = fmaf(z1, m2, acc[1][2]); acc[1][3] = fmaf(z1, m3, acc[1][3]);
            acc[2][0] = fmaf(z2, m0, acc[2][0]); acc[2][1] = fmaf(z2, m1, acc[2][1]);
            acc[2][2] = fmaf(z2, m2, acc[2][2]); acc[2][3] = fmaf(z2, m3, acc[2][3]);
            acc[3][0] = fmaf(z3, m0, acc[3][0]); acc[3][1] = fmaf(z3, m1, acc[3][1]);
            acc[3][2] = fmaf(z3, m2, acc[3][2]); acc[3][3] = fmaf(z3, m3, acc[3][3]);
        }
        __syncthreads();
    }
#pragma unroll
    for (int i = 0; i < 4; ++i) {
        int b = bg * 4 + i;
        float cv = cvec[b];
        float4 o;
        o.x = acc[i][0] + cv; o.y = acc[i][1] + cv;
        o.z = acc[i][2] + cv; o.w = acc[i][3] + cv;
        *(float4*)&y[(size_t)b * G_ + g0 + gg * 4] = o;
    }
}

// ---------------------------------------------------------------------------
extern "C" void kernel_launch(void* const* d_in, const int* in_sizes, int n_in,
                              void* d_out, int out_size, void* d_ws, size_t ws_size,
                              hipStream_t stream) {
    const float* ctl   = (const float*)d_in[0];
    const float* dt    = (const float*)d_in[1];
    const int*   cidx  = (const int*)d_in[2];
    // d_in[3] = drug_fp (unused by the forward pass)
    const float* M     = (const float*)d_in[4];
    const float* A     = (const float*)d_in[5];
    const float* W_in  = (const float*)d_in[6];
    const float* b_in  = (const float*)d_in[7];
    const float* cemb  = (const float*)d_in[8];
    const float* W_out = (const float*)d_in[9];
    const float* b_out = (const float*)d_in[10];
    float* y = (float*)d_out;

    // workspace layout (~17.5 MB total, 256B-aligned blocks)
    char* ws = (char*)d_ws;
    size_t o = 0;
    auto take = [&](size_t bytes) { char* p = ws + o; o = (o + bytes + 255) & ~(size_t)255; return p; };
    float* ctlT     = (float*)take((size_t)G_ * B_ * 4);
    float* dtT      = (float*)take((size_t)G_ * B_ * 4);
    int*   hist     = (int*)  take((size_t)NCH * K_ * 4);
    int*   colstart = (int*)  take(K_ * 4);
    int*   colcnt   = (int*)  take(K_ * 4);
    float* invdeg   = (float*)take(K_ * 4);
    float* cvec     = (float*)take(B_ * 4);
    int*   csc      = (int*)  take((size_t)CSC_CAP * 4);
    float* sout     = (float*)take((size_t)K_ * B_ * 4);
    float* zpA      = (float*)take((size_t)8 * K_ * B_ * 4);
    float* zpB      = (float*)take((size_t)8 * K_ * B_ * 4);
    float* zfinal   = (float*)take((size_t)K_ * B_ * 4);
    (void)ws_size; (void)in_sizes; (void)n_in; (void)out_size;

    // 1. column histogram of M (also = column degree counts)
    k_hist<<<NCH, K_, 0, stream>>>(M, hist);
    // 2. transpose ctl / drug_targets (independent of 1)
    k_trans<<<dim3(G_ / 32, B_ / 32, 2), dim3(32, 8), 0, stream>>>(ctl, dt, ctlT, dtT);
    // 3. scan: inv_deg, CSC bases, cvec
    k_scan<<<1, K_, 0, stream>>>(hist, colstart, colcnt, invdeg, cvec,
                                 cidx, cemb, W_out, b_out);
    // 4. deterministic CSC fill
    k_fill<<<NCH, K_, 0, stream>>>(M, hist, csc);
    // 5. sparse module aggregation + fused MLP + W_out fold -> s [K][B]
    k_gather<<<K_, B_, 0, stream>>>(csc, colstart, colcnt, invdeg,
                                    ctlT, dtT, W_in, b_in, W_out, sout);
    // 6. 10 diffusion steps on z (k-split into 8 partials, ping-pong)
    const float* zin = sout;
    int part = 0;
    float* buf[2] = {zpA, zpB};
    for (int t = 0; t < 10; ++t) {
        float* zo = buf[t & 1];
        k_diff<<<dim3(K_ / 64, B_ / 32, 8), 128, 0, stream>>>(zin, part, A, sout, zo);
        zin = zo;
        part = 1;
    }
    // 7. reduce partials -> zfinal [K][B]
    k_zred<<<(K_ * B_) / (256 * 4), 256, 0, stream>>>(buf[1], zfinal);
    // 8. y = zfinal^T-gather over M + cvec
    k_out<<<G_ / 32, 256, 0, stream>>>(zfinal, M, cvec, y);
}